// Round 5
// baseline (795.652 us; speedup 1.0000x reference)
//
#include <hip/hip_runtime.h>
#include <hip/hip_bf16.h>
#include <math.h>

// Problem constants (from reference): N=524288, D=64, H=128, E=8, A=18
#define DD 64
#define HH 128
#define EE 8
#define AA 18
#define BN_EPS 1e-5f

// Near-tie margin: realistic f32 logit error ~3e-7 rms (worst ~1e-6);
// 5e-5 is ~50-170x safety; ~0.05% of rows get flagged for f64 fixup.
#define TIE_MARGIN 5e-5f

// Per-expert LDS stride: 18*64=1152 floats, +4 pad so 1156 % 32 == 4 →
// each expert e maps its columns to bank offset 4e (all 8 distinct) →
// conflict-free ds_read_b128 across divergent expert indices.
#define WE_STRIDE 1156

// ---------------- HOT KERNEL: pure f32, no cold path ----------------
// R2/R4 lesson: any high-pressure code inside x[]'s live range makes the
// allocator spill the whole 64-reg row array to scratch (+134 MB traffic).
// So this kernel contains ONLY the hot math; near-ties are flagged to ws.
__global__ __launch_bounds__(256, 2) void moe_hot(
    const float* __restrict__ X,
    const float* __restrict__ W1,
    const float* __restrict__ b1,
    const float* __restrict__ gamma,
    const float* __restrict__ beta,
    const float* __restrict__ rmean,
    const float* __restrict__ rvar,
    const float* __restrict__ W2,
    const float* __restrict__ b2,
    const float* __restrict__ We,
    float* __restrict__ out,      // [N, AA]
    float* __restrict__ ret,      // [N, EE]
    int* __restrict__ flags,      // [N] 1 = near-tie, needs f64 fixup
    int Ntot)
{
    __shared__ float sWe[EE * WE_STRIDE];

    const int tid = threadIdx.x;
    const int n = blockIdx.x * 256 + tid;

    // Issue X row loads first (global latency overlaps the staging loop).
    float4 x[16];
    if (n < Ntot) {
        const float4* xv = (const float4*)(X + (size_t)n * DD);
        #pragma unroll
        for (int k = 0; k < 16; ++k) x[k] = xv[k];
    }

    // Stage We into LDS (coalesced read, padded write).
    for (int i = tid; i < EE * AA * DD; i += 256) {
        int e = i / (AA * DD);
        int r = i - e * (AA * DD);
        sWe[e * WE_STRIDE + r] = We[i];
    }

    __syncthreads();

    if (n >= Ntot) return;

    // ---- h = relu(BN(X @ W1^T + b1)); logits = h @ W2^T + b2 (f32) ----
    float logits[EE];
    #pragma unroll
    for (int e = 0; e < EE; ++e) logits[e] = b2[e];

    #pragma unroll 2
    for (int j = 0; j < HH; ++j) {
        const float4* wv = (const float4*)(W1 + j * DD);  // uniform -> s_load
        float s0 = 0.f, s1 = 0.f, s2 = 0.f, s3 = 0.f;
        #pragma unroll
        for (int k = 0; k < 16; ++k) {
            float4 w = wv[k];
            s0 = fmaf(x[k].x, w.x, s0);
            s1 = fmaf(x[k].y, w.y, s1);
            s2 = fmaf(x[k].z, w.z, s2);
            s3 = fmaf(x[k].w, w.w, s3);
        }
        float h = ((s0 + s1) + (s2 + s3)) + b1[j];
        float sc = gamma[j] * rsqrtf(rvar[j] + BN_EPS);
        float hb = fmaf(h - rmean[j], sc, beta[j]);
        hb = fmaxf(hb, 0.f);
        #pragma unroll
        for (int e = 0; e < EE; ++e)
            logits[e] = fmaf(hb, W2[e * HH + j], logits[e]);  // uniform -> s_load
    }

    // ---- f32 argmax (first index wins, matches np argmax) + tie gap ----
    int emax = 0;
    float lmax = logits[0];
    #pragma unroll
    for (int e = 1; e < EE; ++e) {
        if (logits[e] > lmax) { lmax = logits[e]; emax = e; }
    }
    float second = -INFINITY;
    #pragma unroll
    for (int e = 0; e < EE; ++e) {
        if (e != emax && logits[e] > second) second = logits[e];
    }
    flags[n] = (lmax - second < TIE_MARGIN) ? 1 : 0;

    // ---- ret = one_hot(emax) (straight-through == exact one-hot) ----
    float4* retv = (float4*)(ret + (size_t)n * EE);
    retv[0] = make_float4(emax == 0 ? 1.f : 0.f, emax == 1 ? 1.f : 0.f,
                          emax == 2 ? 1.f : 0.f, emax == 3 ? 1.f : 0.f);
    retv[1] = make_float4(emax == 4 ? 1.f : 0.f, emax == 5 ? 1.f : 0.f,
                          emax == 6 ? 1.f : 0.f, emax == 7 ? 1.f : 0.f);

    // ---- output[a] = dot(X_row, We[emax][a][:]) ----
    const float* wexp = &sWe[emax * WE_STRIDE];
    float outv[AA];
    #pragma unroll
    for (int a = 0; a < AA; ++a) {
        const float4* wv = (const float4*)(wexp + a * DD);  // 16B-aligned LDS
        float s0 = 0.f, s1 = 0.f, s2 = 0.f, s3 = 0.f;
        #pragma unroll
        for (int k = 0; k < 16; ++k) {
            float4 w = wv[k];
            s0 = fmaf(x[k].x, w.x, s0);
            s1 = fmaf(x[k].y, w.y, s1);
            s2 = fmaf(x[k].z, w.z, s2);
            s3 = fmaf(x[k].w, w.w, s3);
        }
        outv[a] = (s0 + s1) + (s2 + s3);
    }
    float2* ov = (float2*)(out + (size_t)n * AA);  // 72B row stride, 8B-aligned
    #pragma unroll
    for (int a2 = 0; a2 < 9; ++a2)
        ov[a2] = make_float2(outv[2 * a2], outv[2 * a2 + 1]);
}

// ---------------- FIXUP KERNEL: f64 argmax for flagged rows ----------------
__global__ __launch_bounds__(256, 2) void moe_fix(
    const float* __restrict__ X,
    const float* __restrict__ W1,
    const float* __restrict__ b1,
    const float* __restrict__ gamma,
    const float* __restrict__ beta,
    const float* __restrict__ rmean,
    const float* __restrict__ rvar,
    const float* __restrict__ W2,
    const float* __restrict__ b2,
    const float* __restrict__ We,
    float* __restrict__ out,
    float* __restrict__ ret,
    const int* __restrict__ flags,
    int Ntot)
{
    const int n = blockIdx.x * 256 + threadIdx.x;
    if (n >= Ntot) return;
    if (flags[n] == 0) return;   // ~99.95% of threads exit here

    const float* xg = X + (size_t)n * DD;

    // f64 logits — resolves the near-tie the way the reference's argmax does.
    double ld[EE];
    #pragma unroll
    for (int e = 0; e < EE; ++e) ld[e] = (double)b2[e];
    for (int j = 0; j < HH; ++j) {
        const float* w = W1 + j * DD;
        double hd = 0.0;
        for (int k = 0; k < DD; ++k)
            hd += (double)xg[k] * (double)w[k];
        hd += (double)b1[j];
        double sc = (double)gamma[j] / sqrt((double)rvar[j] + 1e-5);
        double hb = (hd - (double)rmean[j]) * sc + (double)beta[j];
        hb = hb > 0.0 ? hb : 0.0;
        #pragma unroll
        for (int e = 0; e < EE; ++e)
            ld[e] += hb * (double)W2[e * HH + j];
    }
    int emax = 0;
    double lm = ld[0];
    #pragma unroll
    for (int e = 1; e < EE; ++e) {
        if (ld[e] > lm) { lm = ld[e]; emax = e; }
    }

    // Rewrite ret row.
    float4* retv = (float4*)(ret + (size_t)n * EE);
    retv[0] = make_float4(emax == 0 ? 1.f : 0.f, emax == 1 ? 1.f : 0.f,
                          emax == 2 ? 1.f : 0.f, emax == 3 ? 1.f : 0.f);
    retv[1] = make_float4(emax == 4 ? 1.f : 0.f, emax == 5 ? 1.f : 0.f,
                          emax == 6 ? 1.f : 0.f, emax == 7 ? 1.f : 0.f);

    // Rewrite out row — same f32 pairwise order as the hot kernel so
    // unflipped flagged rows reproduce bit-identical values.
    float4 x[16];
    const float4* xv = (const float4*)xg;
    #pragma unroll
    for (int k = 0; k < 16; ++k) x[k] = xv[k];

    const float* wexp = We + (size_t)emax * AA * DD;
    float outv[AA];
    #pragma unroll
    for (int a = 0; a < AA; ++a) {
        const float4* wv = (const float4*)(wexp + a * DD);
        float s0 = 0.f, s1 = 0.f, s2 = 0.f, s3 = 0.f;
        #pragma unroll
        for (int k = 0; k < 16; ++k) {
            float4 w = wv[k];
            s0 = fmaf(x[k].x, w.x, s0);
            s1 = fmaf(x[k].y, w.y, s1);
            s2 = fmaf(x[k].z, w.z, s2);
            s3 = fmaf(x[k].w, w.w, s3);
        }
        outv[a] = (s0 + s1) + (s2 + s3);
    }
    float2* ov = (float2*)(out + (size_t)n * AA);
    #pragma unroll
    for (int a2 = 0; a2 < 9; ++a2)
        ov[a2] = make_float2(outv[2 * a2], outv[2 * a2 + 1]);
}

extern "C" void kernel_launch(void* const* d_in, const int* in_sizes, int n_in,
                              void* d_out, int out_size, void* d_ws, size_t ws_size,
                              hipStream_t stream) {
    const float* X     = (const float*)d_in[0];
    const float* W1    = (const float*)d_in[1];
    const float* b1    = (const float*)d_in[2];
    const float* gamma = (const float*)d_in[3];
    const float* beta  = (const float*)d_in[4];
    const float* rmean = (const float*)d_in[5];
    const float* rvar  = (const float*)d_in[6];
    const float* W2    = (const float*)d_in[7];
    const float* b2    = (const float*)d_in[8];
    const float* We    = (const float*)d_in[9];

    const int Ntot = in_sizes[0] / DD;          // 524288
    float* out = (float*)d_out;                 // [N, AA] first
    float* ret = out + (size_t)Ntot * AA;       // then [N, EE]
    int* flags = (int*)d_ws;                    // [N] ints (2 MB)

    const int nblocks = (Ntot + 255) / 256;     // 2048
    moe_hot<<<nblocks, 256, 0, stream>>>(
        X, W1, b1, gamma, beta, rmean, rvar, W2, b2, We, out, ret, flags, Ntot);
    moe_fix<<<nblocks, 256, 0, stream>>>(
        X, W1, b1, gamma, beta, rmean, rvar, W2, b2, We, out, ret, flags, Ntot);
}

// Round 6
// 670.494 us; speedup vs baseline: 1.1867x; 1.1867x over previous
//
#include <hip/hip_runtime.h>
#include <hip/hip_bf16.h>
#include <math.h>

// Problem constants: N=524288, D=64, H=128, E=8, A=18
#define DD 64
#define HH 128
#define EE 8
#define AA 18
#define BN_EPS 1e-5f

// Near-tie margin: f32 logit error worst ~1e-6; 5e-5 = ~50x safety,
// flags ~0.05% of rows for the f64 fixup.
#define TIE_MARGIN 5e-5f

// Per-expert LDS stride: 1152 floats + 4 pad → 1156 % 32 == 4: the 8
// experts land on distinct bank quartets → conflict-free divergent reads.
#define WE_STRIDE 1156

#define ROWS_PER_BLOCK 512   // 256 threads x 2 rows

__global__ void zero_count(int* count) { if (threadIdx.x == 0) *count = 0; }

// ---------------- HOT KERNEL: pure f32, 2 rows/thread ----------------
// R2/R4 lesson: no f64 / address-taking inside x-row live ranges (spill).
// R5 lesson: latency-bound on the per-j W1 scalar-load stream → amortize
// one weight stream over 2 rows of FMAs.
__global__ __launch_bounds__(256, 2) void moe_hot(
    const float* __restrict__ X,
    const float* __restrict__ W1,
    const float* __restrict__ b1,
    const float* __restrict__ gamma,
    const float* __restrict__ beta,
    const float* __restrict__ rmean,
    const float* __restrict__ rvar,
    const float* __restrict__ W2,
    const float* __restrict__ b2,
    const float* __restrict__ We,
    float* __restrict__ out,      // [N, AA]
    float* __restrict__ ret,      // [N, EE]
    int* __restrict__ count,      // worklist counter
    int* __restrict__ list,       // worklist of near-tie rows
    int Ntot)
{
    __shared__ float sWe[EE * WE_STRIDE];

    const int tid = threadIdx.x;
    const int na = blockIdx.x * ROWS_PER_BLOCK + tid;        // row A
    const int nb = na + 256;                                 // row B

    // Issue both X-row loads first (overlap with We staging).
    float4 xa[16], xb[16];
    if (na < Ntot) {
        const float4* va = (const float4*)(X + (size_t)na * DD);
        #pragma unroll
        for (int k = 0; k < 16; ++k) xa[k] = va[k];
    }
    if (nb < Ntot) {
        const float4* vb = (const float4*)(X + (size_t)nb * DD);
        #pragma unroll
        for (int k = 0; k < 16; ++k) xb[k] = vb[k];
    }

    // Stage We into LDS (coalesced read, padded write).
    for (int i = tid; i < EE * AA * DD; i += 256) {
        int e = i / (AA * DD);
        int r = i - e * (AA * DD);
        sWe[e * WE_STRIDE + r] = We[i];
    }

    __syncthreads();

    if (na >= Ntot) return;
    const bool hasB = (nb < Ntot);

    float lA[EE], lB[EE];
    #pragma unroll
    for (int e = 0; e < EE; ++e) { lA[e] = b2[e]; lB[e] = b2[e]; }

    for (int j = 0; j < HH; ++j) {
        const float4* wv = (const float4*)(W1 + j * DD);  // uniform -> s_load
        float a0 = 0.f, a1 = 0.f, a2 = 0.f, a3 = 0.f;
        float c0 = 0.f, c1 = 0.f, c2 = 0.f, c3 = 0.f;
        #pragma unroll
        for (int k = 0; k < 16; ++k) {
            float4 w = wv[k];
            a0 = fmaf(xa[k].x, w.x, a0);
            a1 = fmaf(xa[k].y, w.y, a1);
            a2 = fmaf(xa[k].z, w.z, a2);
            a3 = fmaf(xa[k].w, w.w, a3);
            c0 = fmaf(xb[k].x, w.x, c0);
            c1 = fmaf(xb[k].y, w.y, c1);
            c2 = fmaf(xb[k].z, w.z, c2);
            c3 = fmaf(xb[k].w, w.w, c3);
        }
        float sc = gamma[j] * rsqrtf(rvar[j] + BN_EPS);
        float off = beta[j] - (rmean[j] - b1[j]) * sc;   // fold b1+BN: hb = h*sc+off
        float hA = fmaxf(fmaf(((a0 + a1) + (a2 + a3)), sc, off), 0.f);
        float hB = fmaxf(fmaf(((c0 + c1) + (c2 + c3)), sc, off), 0.f);
        #pragma unroll
        for (int e = 0; e < EE; ++e) {
            float w2 = W2[e * HH + j];                   // uniform -> s_load
            lA[e] = fmaf(hA, w2, lA[e]);
            lB[e] = fmaf(hB, w2, lB[e]);
        }
    }

    // ---- argmax (first index wins, strict >, matches np) + tie flag ----
    int eA = 0; float mA = lA[0];
    #pragma unroll
    for (int e = 1; e < EE; ++e) if (lA[e] > mA) { mA = lA[e]; eA = e; }
    float sA = -INFINITY;
    #pragma unroll
    for (int e = 0; e < EE; ++e) if (e != eA && lA[e] > sA) sA = lA[e];
    if (mA - sA < TIE_MARGIN) { int p = atomicAdd(count, 1); list[p] = na; }

    int eB = 0; float mB = lB[0];
    #pragma unroll
    for (int e = 1; e < EE; ++e) if (lB[e] > mB) { mB = lB[e]; eB = e; }
    float sB = -INFINITY;
    #pragma unroll
    for (int e = 0; e < EE; ++e) if (e != eB && lB[e] > sB) sB = lB[e];
    if (hasB && (mB - sB < TIE_MARGIN)) { int p = atomicAdd(count, 1); list[p] = nb; }

    // ---- ret rows (exact one-hot) ----
    float4* rA = (float4*)(ret + (size_t)na * EE);
    rA[0] = make_float4(eA == 0 ? 1.f : 0.f, eA == 1 ? 1.f : 0.f,
                        eA == 2 ? 1.f : 0.f, eA == 3 ? 1.f : 0.f);
    rA[1] = make_float4(eA == 4 ? 1.f : 0.f, eA == 5 ? 1.f : 0.f,
                        eA == 6 ? 1.f : 0.f, eA == 7 ? 1.f : 0.f);
    if (hasB) {
        float4* rB = (float4*)(ret + (size_t)nb * EE);
        rB[0] = make_float4(eB == 0 ? 1.f : 0.f, eB == 1 ? 1.f : 0.f,
                            eB == 2 ? 1.f : 0.f, eB == 3 ? 1.f : 0.f);
        rB[1] = make_float4(eB == 4 ? 1.f : 0.f, eB == 5 ? 1.f : 0.f,
                            eB == 6 ? 1.f : 0.f, eB == 7 ? 1.f : 0.f);
    }

    // ---- output rows: out[n][a] = dot(x_n, We[emax][a]) ----
    {
        const float* wexp = &sWe[eA * WE_STRIDE];
        float ov[AA];
        #pragma unroll
        for (int a = 0; a < AA; ++a) {
            const float4* wv = (const float4*)(wexp + a * DD);
            float s0 = 0.f, s1 = 0.f, s2 = 0.f, s3 = 0.f;
            #pragma unroll
            for (int k = 0; k < 16; ++k) {
                float4 w = wv[k];
                s0 = fmaf(xa[k].x, w.x, s0);
                s1 = fmaf(xa[k].y, w.y, s1);
                s2 = fmaf(xa[k].z, w.z, s2);
                s3 = fmaf(xa[k].w, w.w, s3);
            }
            ov[a] = (s0 + s1) + (s2 + s3);
        }
        float2* po = (float2*)(out + (size_t)na * AA);
        #pragma unroll
        for (int q = 0; q < 9; ++q) po[q] = make_float2(ov[2 * q], ov[2 * q + 1]);
    }
    if (hasB) {
        const float* wexp = &sWe[eB * WE_STRIDE];
        float ov[AA];
        #pragma unroll
        for (int a = 0; a < AA; ++a) {
            const float4* wv = (const float4*)(wexp + a * DD);
            float s0 = 0.f, s1 = 0.f, s2 = 0.f, s3 = 0.f;
            #pragma unroll
            for (int k = 0; k < 16; ++k) {
                float4 w = wv[k];
                s0 = fmaf(xb[k].x, w.x, s0);
                s1 = fmaf(xb[k].y, w.y, s1);
                s2 = fmaf(xb[k].z, w.z, s2);
                s3 = fmaf(xb[k].w, w.w, s3);
            }
            ov[a] = (s0 + s1) + (s2 + s3);
        }
        float2* po = (float2*)(out + (size_t)nb * AA);
        #pragma unroll
        for (int q = 0; q < 9; ++q) po[q] = make_float2(ov[2 * q], ov[2 * q + 1]);
    }
}

// -------- FIXUP: f64 argmax for worklist rows (fixed small grid) --------
__global__ __launch_bounds__(256, 1) void moe_fix(
    const float* __restrict__ X,
    const float* __restrict__ W1,
    const float* __restrict__ b1,
    const float* __restrict__ gamma,
    const float* __restrict__ beta,
    const float* __restrict__ rmean,
    const float* __restrict__ rvar,
    const float* __restrict__ W2,
    const float* __restrict__ b2,
    const float* __restrict__ We,
    float* __restrict__ out,
    float* __restrict__ ret,
    const int* __restrict__ count,
    const int* __restrict__ list)
{
    const int nwork = *count;
    for (int i = blockIdx.x * 256 + threadIdx.x; i < nwork; i += gridDim.x * 256) {
        const int n = list[i];
        const float* xg = X + (size_t)n * DD;

        double ld[EE];
        #pragma unroll
        for (int e = 0; e < EE; ++e) ld[e] = (double)b2[e];
        for (int j = 0; j < HH; ++j) {
            const float* w = W1 + j * DD;
            double hd = 0.0;
            for (int k = 0; k < DD; ++k)
                hd += (double)xg[k] * (double)w[k];
            hd += (double)b1[j];
            double sc = (double)gamma[j] / sqrt((double)rvar[j] + 1e-5);
            double hb = (hd - (double)rmean[j]) * sc + (double)beta[j];
            hb = hb > 0.0 ? hb : 0.0;
            #pragma unroll
            for (int e = 0; e < EE; ++e)
                ld[e] += hb * (double)W2[e * HH + j];
        }
        int emax = 0;
        double lm = ld[0];
        #pragma unroll
        for (int e = 1; e < EE; ++e) if (ld[e] > lm) { lm = ld[e]; emax = e; }

        float4* rp = (float4*)(ret + (size_t)n * EE);
        rp[0] = make_float4(emax == 0 ? 1.f : 0.f, emax == 1 ? 1.f : 0.f,
                            emax == 2 ? 1.f : 0.f, emax == 3 ? 1.f : 0.f);
        rp[1] = make_float4(emax == 4 ? 1.f : 0.f, emax == 5 ? 1.f : 0.f,
                            emax == 6 ? 1.f : 0.f, emax == 7 ? 1.f : 0.f);

        // Same f32 pairwise order as hot kernel (bit-identical for unflipped rows).
        const float* wexp = We + (size_t)emax * AA * DD;
        float ov[AA];
        #pragma unroll
        for (int a = 0; a < AA; ++a) {
            const float* wr = wexp + a * DD;
            float s0 = 0.f, s1 = 0.f, s2 = 0.f, s3 = 0.f;
            for (int k = 0; k < 16; ++k) {
                s0 = fmaf(xg[4 * k + 0], wr[4 * k + 0], s0);
                s1 = fmaf(xg[4 * k + 1], wr[4 * k + 1], s1);
                s2 = fmaf(xg[4 * k + 2], wr[4 * k + 2], s2);
                s3 = fmaf(xg[4 * k + 3], wr[4 * k + 3], s3);
            }
            ov[a] = (s0 + s1) + (s2 + s3);
        }
        float* po = out + (size_t)n * AA;
        #pragma unroll
        for (int a = 0; a < AA; ++a) po[a] = ov[a];
    }
}

extern "C" void kernel_launch(void* const* d_in, const int* in_sizes, int n_in,
                              void* d_out, int out_size, void* d_ws, size_t ws_size,
                              hipStream_t stream) {
    const float* X     = (const float*)d_in[0];
    const float* W1    = (const float*)d_in[1];
    const float* b1    = (const float*)d_in[2];
    const float* gamma = (const float*)d_in[3];
    const float* beta  = (const float*)d_in[4];
    const float* rmean = (const float*)d_in[5];
    const float* rvar  = (const float*)d_in[6];
    const float* W2    = (const float*)d_in[7];
    const float* b2    = (const float*)d_in[8];
    const float* We    = (const float*)d_in[9];

    const int Ntot = in_sizes[0] / DD;          // 524288
    float* out = (float*)d_out;                 // [N, AA] first
    float* ret = out + (size_t)Ntot * AA;       // then [N, EE]
    int* count = (int*)d_ws;                    // worklist counter
    int* list  = (int*)d_ws + 16;               // worklist (worst case N ints)

    zero_count<<<1, 64, 0, stream>>>(count);

    const int nblocks = (Ntot + ROWS_PER_BLOCK - 1) / ROWS_PER_BLOCK;  // 1024
    moe_hot<<<nblocks, 256, 0, stream>>>(
        X, W1, b1, gamma, beta, rmean, rvar, W2, b2, We, out, ret, count, list, Ntot);
    moe_fix<<<16, 256, 0, stream>>>(
        X, W1, b1, gamma, beta, rmean, rvar, W2, b2, We, out, ret, count, list);
}